// Round 14
// baseline (261.086 us; speedup 1.0000x reference)
//
#include <hip/hip_runtime.h>
#include <hip/hip_bf16.h>
#include <math.h>

// Problem constants
#define B_    32
#define N_    1024
#define DIM_  512
#define HEAD_ 8
#define HD_   64        // head dim
#define WSP   32        // sqrt(N)
#define M2    256       // kv spatial positions (16*16)
#define CDIM  1024      // 2*DIM
#define KCONV 4608      // DIM*3*3
#define KHALF 2304      // conv K-split chunk
#define EPS_  1e-5f
#define SCALE_ 0.044194173824159216f  // DIM^-0.5
#define PW    34        // padded spatial side (32 + 2 halo)

typedef __attribute__((ext_vector_type(8))) short bf16x8;
typedef __attribute__((ext_vector_type(4))) float f32x4_t;
typedef const __attribute__((address_space(1))) void gas_t;   // global addr space
typedef __attribute__((address_space(3))) void las_t;         // LDS addr space

__device__ __forceinline__ ushort f2b(float x) {
  __hip_bfloat16 h = __float2bfloat16(x);
  return *reinterpret_cast<const ushort*>(&h);
}

// ---------------------------------------------------------------------------
// Merged prep: blocks [0,1056) zero featsp halo border;
// [1056,1312) cast W_q -> bf16; [1312,1568) cast W_out -> bf16.
// ---------------------------------------------------------------------------
__global__ __launch_bounds__(256) void misc_prep_kernel(
    ushort* __restrict__ featsp, const float* __restrict__ W_q,
    ushort* __restrict__ wqb, const float* __restrict__ W_out,
    ushort* __restrict__ woutb) {
  int blk = blockIdx.x;
  if (blk < 1056) {
    int t = blk * 256 + threadIdx.x;           // 270336 = 32*8448 exact
    int b = t / 8448, r = t - b * 8448;        // 8448 = 132*64
    int cell = r >> 6, ic8 = (r & 63) * 8;
    int iw, ih;
    if (cell < 34)      { iw = 0;  ih = cell; }
    else if (cell < 68) { iw = 33; ih = cell - 34; }
    else { int e = cell - 68; iw = 1 + (e >> 1); ih = (e & 1) * 33; }
    bf16x8 z = {};
    *reinterpret_cast<bf16x8*>(&featsp[(((size_t)b * PW + iw) * PW + ih) * 512 + ic8]) = z;
  } else if (blk < 1312) {
    int i = (blk - 1056) * 256 + threadIdx.x;  // [0, 65536)
    float4 v = reinterpret_cast<const float4*>(W_q)[i];
    ushort4 o;
    o.x = f2b(v.x); o.y = f2b(v.y); o.z = f2b(v.z); o.w = f2b(v.w);
    reinterpret_cast<ushort4*>(wqb)[i] = o;
  } else {
    int i = (blk - 1312) * 256 + threadIdx.x;
    float4 v = reinterpret_cast<const float4*>(W_out)[i];
    ushort4 o;
    o.x = f2b(v.x); o.y = f2b(v.y); o.z = f2b(v.z); o.w = f2b(v.w);
    reinterpret_cast<ushort4*>(woutb)[i] = o;
  }
}

// ---------------------------------------------------------------------------
// feats f32 [b][n=iw*32+ih][ic] -> zero-padded bf16 [b][iw+1][ih+1][ic]
// ---------------------------------------------------------------------------
__global__ __launch_bounds__(256) void cast_featsp_kernel(
    const float* __restrict__ feats, ushort* __restrict__ featsp) {
  int i = blockIdx.x * 256 + threadIdx.x;       // ushort4 index
  int e = i * 4;
  int b = e >> 19, r = e & 524287;
  int n = r >> 9, ic = r & 511;
  int iw = n >> 5, ih = n & 31;
  float4 v = reinterpret_cast<const float4*>(feats)[i];
  ushort4 o;
  o.x = f2b(v.x); o.y = f2b(v.y); o.z = f2b(v.z); o.w = f2b(v.w);
  size_t dst = (((size_t)b * PW + iw + 1) * PW + ih + 1) * 512 + ic;
  *reinterpret_cast<ushort4*>(&featsp[dst]) = o;
}

// ---------------------------------------------------------------------------
// conv_w [oc][ic*9 + tap] fp32 -> bf16 [oc][tap*512 + ic]
// ---------------------------------------------------------------------------
__global__ __launch_bounds__(256) void permute_convw_kernel(
    const float* __restrict__ in, ushort* __restrict__ out) {
  int oc = blockIdx.y;
  int idx = blockIdx.x * 256 + threadIdx.x;  // [0, 4608)
  int tap = idx >> 9, ic = idx & 511;
  out[(size_t)oc * KCONV + idx] = f2b(in[(size_t)oc * KCONV + ic * 9 + tap]);
}

// ---------------------------------------------------------------------------
// conv 256x256 tile, BK=64, 8 waves, 8-PHASE half-tile pipeline (T3+T4):
// LDS = 4-slot ring, slot 32KB = A-half[256 rows][32 k] + B-half[256][32].
// Half h (72 per z-slice): 4 phases, each {ds_read 2 A-frags (+4 B at p0),
// issue 1 of half h+3's 4 gloads, s_barrier, lgkmcnt(0)+sched_barrier,
// setprio(1), 8 MFMA, setprio(0), s_barrier}. Counted vmcnt(8) only at the
// half boundary (4 loads/half x 2 halves in flight) - never drained in-loop.
// Bank-free layout: logical (r,c) at phys chunk (o*4+c)^(q&7), q=r>>1,o=r&1
// (source-permuted for linear gload_lds dest; same involution on read).
// z==0 writes kvf (+bias), z==1 writes kvp1; LN sums.
// ---------------------------------------------------------------------------
__global__ __launch_bounds__(512, 2) void conv256_kernel(
    const ushort* __restrict__ featsp, const ushort* __restrict__ convwb,
    const float* __restrict__ conv_b, float* __restrict__ kvf,
    float* __restrict__ kvp1) {
  __shared__ __align__(16) ushort lds[4][16384];   // 4 slots x 32 KB
  const int tid = threadIdx.x;                 // 0..511
  const int lane = tid & 63, wid = tid >> 6;   // 8 waves
  const int wr = wid >> 2, wc = wid & 3;       // 2M x 4N
  const int lrow = lane & 15, lk = lane >> 4;
  const int kz = blockIdx.z;
  const int koff = kz * KHALF;

  // XCD swizzle within z-slice (nwg=128, %8==0 -> bijective)
  const int l = blockIdx.y * gridDim.x + blockIdx.x;   // 0..127
  const int v = (l & 7) * 16 + (l >> 3);
  const int bm = (v >> 2) * 256;               // nbn = 4
  const int bn = (v & 3) * 256;
  const int bimg = bm >> 8;                    // one image per bm-tile

  f32x4_t acc[8][4] = {};

  // issue load-instr j (0..3) for global half hh into slot hh&3
  auto stage1 = [&](int hh, int j) {
    int slot = hh & 3;
    int kbase = koff + hh * 32;
    if (j < 2) {                               // A-half: 1024 16B slots
      int s = j * 512 + tid;
      int q = s >> 3, e = s & 7;
      int el = e ^ (q & 7);
      int r = q * 2 + (el >> 2);
      int c = el & 3;
      int kk2 = kbase + c * 8;
      int tap = kk2 >> 9, ic = kk2 & 511;
      int kh = tap / 3, kw = tap - 3 * kh;
      int w2 = r >> 4, h2 = r & 15;
      const ushort* ga = &featsp[(((size_t)bimg * PW + 2 * w2 + kh) * PW + 2 * h2 + kw) * 512 + ic];
      __builtin_amdgcn_global_load_lds((gas_t*)ga,
          (las_t*)(&lds[slot][0] + (size_t)s * 8), 16, 0, 0);
    } else {                                   // B-half
      int s = (j - 2) * 512 + tid;
      int q = s >> 3, e = s & 7;
      int el = e ^ (q & 7);
      int r = q * 2 + (el >> 2);
      int c = el & 3;
      const ushort* gb = &convwb[(size_t)(bn + r) * KCONV + kbase + c * 8];
      __builtin_amdgcn_global_load_lds((gas_t*)gb,
          (las_t*)(&lds[slot][8192] + (size_t)s * 8), 16, 0, 0);
    }
  };

  auto rdA = [&](int slot, int mf) -> bf16x8 {
    int r = wr * 128 + mf * 16 + lrow;
    int q = r >> 1, o = r & 1;
    int e = (o * 4 + lk) ^ (q & 7);
    return *reinterpret_cast<const bf16x8*>(&lds[slot][q * 64 + e * 8]);
  };
  auto rdB = [&](int slot, int nf) -> bf16x8 {
    int r = wc * 64 + nf * 16 + lrow;
    int q = r >> 1, o = r & 1;
    int e = (o * 4 + lk) ^ (q & 7);
    return *reinterpret_cast<const bf16x8*>(&lds[slot][8192 + q * 64 + e * 8]);
  };

  const int H = KHALF / 32;                    // 72 halves
  // prologue: issue halves 0,1,2 (12 wave-loads); retire half 0
#pragma unroll
  for (int hh = 0; hh < 3; ++hh)
#pragma unroll
    for (int j = 0; j < 4; ++j) stage1(hh, j);
  asm volatile("s_waitcnt vmcnt(8)" ::: "memory");
  __builtin_amdgcn_s_barrier();

  for (int h = 0; h < H; ++h) {
    int slot = h & 3;
    bf16x8 bF[4];
#pragma unroll
    for (int p = 0; p < 4; ++p) {
      if (p == 0) {
        bF[0] = rdB(slot, 0); bF[1] = rdB(slot, 1);
        bF[2] = rdB(slot, 2); bF[3] = rdB(slot, 3);
      }
      bf16x8 aa0 = rdA(slot, 2 * p), aa1 = rdA(slot, 2 * p + 1);
      if (h + 3 < H) stage1(h + 3, p);
      __builtin_amdgcn_s_barrier();
      asm volatile("s_waitcnt lgkmcnt(0)" ::: "memory");
      __builtin_amdgcn_sched_barrier(0);
      __builtin_amdgcn_s_setprio(1);
#pragma unroll
      for (int n = 0; n < 4; ++n) {
        acc[2 * p][n]     = __builtin_amdgcn_mfma_f32_16x16x32_bf16(aa0, bF[n], acc[2 * p][n], 0, 0, 0);
        acc[2 * p + 1][n] = __builtin_amdgcn_mfma_f32_16x16x32_bf16(aa1, bF[n], acc[2 * p + 1][n], 0, 0, 0);
      }
      __builtin_amdgcn_s_setprio(0);
      if (p < 3) __builtin_amdgcn_s_barrier();
    }
    // half boundary: retire next half's loads (counted, never deep-drain)
    if (h <= H - 4)      asm volatile("s_waitcnt vmcnt(8)" ::: "memory");
    else if (h == H - 3) asm volatile("s_waitcnt vmcnt(4)" ::: "memory");
    else                 asm volatile("s_waitcnt vmcnt(0)" ::: "memory");
    __builtin_amdgcn_s_barrier();
  }

  float* Co = kz ? kvp1 : kvf;
#pragma unroll
  for (int m = 0; m < 8; ++m) {
#pragma unroll
    for (int n = 0; n < 4; ++n) {
      int col = bn + wc * 64 + n * 16 + lrow;
#pragma unroll
      for (int r = 0; r < 4; ++r) {
        int row = bm + wr * 128 + m * 16 + lk * 4 + r;
        float v2 = acc[m][n][r];
        if (kz == 0) v2 += conv_b[col];
        Co[(size_t)row * CDIM + col] = v2;
      }
    }
  }
}

// ---------------------------------------------------------------------------
// Shared MFMA GEMM body (R10/R12 config) for q-proj and out-proj.
// ---------------------------------------------------------------------------
template<int MODE>
__device__ __forceinline__ void gemm_body(
    ushort (*As)[128][32], ushort (*Bs)[128][32],
    int l, int nbn, int nwg,
    const ushort* __restrict__ A, const ushort* __restrict__ featsp,
    const ushort* __restrict__ Bw, float* __restrict__ Cf,
    ushort* __restrict__ Cb, int M, int N, int K) {
  const int tid = threadIdx.x;
  const int lane = tid & 63, wid = tid >> 6;
  const int wr = wid >> 1, wc = wid & 1;
  const int v = (l & 7) * (nwg >> 3) + (l >> 3);
  const int bm = (v / nbn) * 128, bn = (v % nbn) * 128;
  const int lrow = lane & 15, lk = lane >> 4;
  const int swz = (lrow >> 1) & 3;

  f32x4_t acc[4][4] = {};

  auto stage = [&](int buf, int kt) {
    int k0 = kt << 5;
#pragma unroll
    for (int it = 0; it < 2; ++it) {
      int idx = it * 256 + tid;
      int row = idx >> 2;
      int c = (((idx & 3) ^ ((idx >> 3) & 3))) * 8;
      const ushort* ga;
      if (MODE == 0) {
        ga = &A[(size_t)(bm + row) * K + k0 + c];
      } else {
        int p = bm + row;
        int b = p >> 10, n = p & 1023;
        int iw = n >> 5, ih = n & 31;
        ga = &featsp[(((size_t)b * PW + iw + 1) * PW + ih + 1) * 512 + k0 + c];
      }
      __builtin_amdgcn_global_load_lds((gas_t*)ga,
          (las_t*)(&As[buf][0][0] + (size_t)idx * 8), 16, 0, 0);
      const ushort* gb = &Bw[(size_t)(bn + row) * K + k0 + c];
      __builtin_amdgcn_global_load_lds((gas_t*)gb,
          (las_t*)(&Bs[buf][0][0] + (size_t)idx * 8), 16, 0, 0);
    }
  };

  stage(0, 0);
  const int NT = K >> 5;
  for (int kt = 0; kt < NT; ++kt) {
    int cur = kt & 1;
    if (kt + 1 < NT) {
      stage(cur ^ 1, kt + 1);
      asm volatile("s_waitcnt vmcnt(4)" ::: "memory");
    } else {
      asm volatile("s_waitcnt vmcnt(0)" ::: "memory");
    }
    __builtin_amdgcn_s_barrier();
    __builtin_amdgcn_sched_barrier(0);
    bf16x8 aF[4], bF[4];
#pragma unroll
    for (int m = 0; m < 4; ++m)
      aF[m] = *reinterpret_cast<const bf16x8*>(
          &As[cur][wr * 64 + m * 16 + lrow][(lk ^ swz) * 8]);
#pragma unroll
    for (int n = 0; n < 4; ++n)
      bF[n] = *reinterpret_cast<const bf16x8*>(
          &Bs[cur][wc * 64 + n * 16 + lrow][(lk ^ swz) * 8]);
#pragma unroll
    for (int m = 0; m < 4; ++m)
#pragma unroll
      for (int n = 0; n < 4; ++n)
        acc[m][n] = __builtin_amdgcn_mfma_f32_16x16x32_bf16(
            aF[m], bF[n], acc[m][n], 0, 0, 0);
    __builtin_amdgcn_sched_barrier(0);
    __builtin_amdgcn_s_barrier();
  }

#pragma unroll
  for (int m = 0; m < 4; ++m) {
#pragma unroll
    for (int n = 0; n < 4; ++n) {
      int col = bn + wc * 64 + n * 16 + lrow;
#pragma unroll
      for (int r = 0; r < 4; ++r) {
        int row = bm + wr * 64 + m * 16 + lk * 4 + r;
        float v2 = acc[m][n][r];
        if (MODE == 1) Cb[(size_t)row * N + col] = f2b(v2);
        else Cf[(size_t)row * N + col] = v2;
      }
    }
  }
}

// q-proj (MODE 1)
__global__ __launch_bounds__(256) void qproj_kernel(
    const ushort* __restrict__ featsp, const ushort* __restrict__ wqb,
    ushort* __restrict__ qb) {
  __shared__ ushort As[2][128][32];
  __shared__ ushort Bs[2][128][32];
  int l = blockIdx.y * gridDim.x + blockIdx.x;
  gemm_body<1>(As, Bs, l, gridDim.x, gridDim.x * gridDim.y,
               nullptr, featsp, wqb, nullptr, qb, B_ * N_, DIM_, DIM_);
}

// out-proj (MODE 0)
__global__ __launch_bounds__(256) void gemm0_kernel(
    const ushort* __restrict__ A, const ushort* __restrict__ Bw,
    float* __restrict__ Cf, int M, int N, int K) {
  __shared__ ushort As[2][128][32];
  __shared__ ushort Bs[2][128][32];
  int l = blockIdx.y * gridDim.x + blockIdx.x;
  gemm_body<0>(As, Bs, l, gridDim.x, gridDim.x * gridDim.y,
               A, nullptr, Bw, Cf, nullptr, M, N, K);
}

// ---------------------------------------------------------------------------
// LayerNorm over last dim (1024) of conv partials p0+p1 (f32).
// K half -> Kb[bh][256][64] row-major; V half -> Vt[bh][64][256] transposed.
// ---------------------------------------------------------------------------
__global__ __launch_bounds__(256) void ln_kernel(
    const float* __restrict__ kvp0, const float* __restrict__ kvp1,
    const float* __restrict__ gamma, const float* __restrict__ beta,
    ushort* __restrict__ Kb, ushort* __restrict__ Vt) {
  const int p = blockIdx.x, tid = threadIdx.x;
  float4 a = reinterpret_cast<const float4*>(kvp0 + (size_t)p * CDIM)[tid];
  float4 b4 = reinterpret_cast<const float4*>(kvp1 + (size_t)p * CDIM)[tid];
  float4 x = make_float4(a.x + b4.x, a.y + b4.y, a.z + b4.z, a.w + b4.w);
  float s = x.x + x.y + x.z + x.w;
  float ss = x.x * x.x + x.y * x.y + x.z * x.z + x.w * x.w;
#pragma unroll
  for (int off = 32; off > 0; off >>= 1) {
    s += __shfl_down(s, off);
    ss += __shfl_down(ss, off);
  }
  __shared__ float sb[4], ssb[4];
  if ((tid & 63) == 0) { sb[tid >> 6] = s; ssb[tid >> 6] = ss; }
  __syncthreads();
  float tot = sb[0] + sb[1] + sb[2] + sb[3];
  float tot2 = ssb[0] + ssb[1] + ssb[2] + ssb[3];
  float mu = tot * (1.f / CDIM);
  float var = tot2 * (1.f / CDIM) - mu * mu;
  float rstd = rsqrtf(var + EPS_);
  float4 g = reinterpret_cast<const float4*>(gamma)[tid];
  float4 bb = reinterpret_cast<const float4*>(beta)[tid];
  ushort o0 = f2b((x.x - mu) * rstd * g.x + bb.x);
  ushort o1 = f2b((x.y - mu) * rstd * g.y + bb.y);
  ushort o2 = f2b((x.z - mu) * rstd * g.z + bb.z);
  ushort o3 = f2b((x.w - mu) * rstd * g.w + bb.w);
  int b = p >> 8, j = p & 255;
  int c = tid * 4;
  if (c < DIM_) {
    int h = c >> 6, d = c & 63;
    ushort4 o = make_ushort4(o0, o1, o2, o3);
    *reinterpret_cast<ushort4*>(&Kb[(((size_t)(b * 8 + h)) * M2 + j) * HD_ + d]) = o;
  } else {
    int c2 = c - DIM_;
    int h = c2 >> 6, d = c2 & 63;
    size_t base = ((size_t)(b * 8 + h) * HD_ + d) * M2 + j;
    Vt[base]           = o0;
    Vt[base + M2]      = o1;
    Vt[base + 2 * M2]  = o2;
    Vt[base + 3 * M2]  = o3;
  }
}

// ---------------------------------------------------------------------------
// MFMA attention (R12): ONE block per (b,h), 512 threads = 8 waves, K/V
// staged once, single barrier, per-wave private P. LDS 128 KiB.
// ---------------------------------------------------------------------------
__global__ __launch_bounds__(512, 2) void attn_mfma_kernel(
    const ushort* __restrict__ qb, const ushort* __restrict__ Kb,
    const ushort* __restrict__ Vt, ushort* __restrict__ attob) {
  __shared__ __align__(16) char lds[131072];
  char* lp = lds;
  const int tid = threadIdx.x;
  const int lane = tid & 63, wid = tid >> 6;   // wid 0..7
  const int lr = lane & 15, lk = lane >> 4;
  const int bh = blockIdx.x;
  const int b = bh >> 3, h = bh & 7;

  auto ks_byte = [](int j, int d) -> int {            // K[256][64] @0
    return (j << 7) + (((d << 1)) ^ ((j & 7) << 4));
  };
  auto vt_byte = [](int d, int j) -> int {            // V^T[64][256] @32K
    return 32768 + (d << 9) + (((j << 1)) ^ ((d & 7) << 4));
  };
  auto p_byte = [](int w, int q4, int kv) -> int {    // P per wave @64K
    return 65536 + (w << 13) + (q4 << 9) + (((kv << 1)) ^ ((q4 & 7) << 4));
  };

  const ushort* Khead  = Kb + (size_t)bh * M2 * HD_;   // [256][64]
  const ushort* Vthead = Vt + (size_t)bh * HD_ * M2;   // [64][256]

#pragma unroll
  for (int it = 0; it < 4; ++it) {
    int o = (it * 512 + tid) * 16;
    int j = o >> 7, c = (o >> 4) & 7;
    int cl = c ^ (j & 7);
    __builtin_amdgcn_global_load_lds((gas_t*)(Khead + j * HD_ + cl * 8),
        (las_t*)(lp + o), 16, 0, 0);
  }
#pragma unroll
  for (int it = 0; it < 4; ++it) {
    int o = (it * 512 + tid) * 16;
    int d = o >> 9, c = (o >> 4) & 31;
    int cl = c ^ (d & 7);
    __builtin_amdgcn_global_load_lds((gas_t*)(Vthead + d * M2 + cl * 8),
        (las_t*)(lp + 32768 + o), 16, 0, 0);
  }

  __syncthreads();   // the ONLY block-wide barrier

  for (int qp = 0; qp < 4; ++qp) {
    const int qbase = qp * 256 + wid * 32;
    bf16x8 qf[2][2];
#pragma unroll
    for (int mf = 0; mf < 2; ++mf)
#pragma unroll
      for (int ks = 0; ks < 2; ++ks)
        qf[mf][ks] = *reinterpret_cast<const bf16x8*>(
            qb + ((size_t)(b * N_ + qbase + mf * 16 + lr)) * DIM_ + h * HD_ + ks * 32 + lk * 8);

    f32x4_t sacc[2][16] = {};
    __builtin_amdgcn_s_setprio(1);
#pragma unroll
    for (int ks = 0; ks < 2; ++ks) {
#pragma unroll
      for (int nj = 0; nj < 16; ++nj) {
        bf16x8 kf = *reinterpret_cast<const bf16x8*>(
            lp + ks_byte(nj * 16 + lr, ks * 32 + lk * 8));
        sacc[0][nj] = __builtin_amdgcn_mfma_f32_16x16x32_bf16(qf[0][ks], kf, sacc[0][nj], 0, 0, 0);
        sacc[1][nj] = __builtin_amdgcn_mfma_f32_16x16x32_bf16(qf[1][ks], kf, sacc[1][nj], 0, 0, 0);
      }
    }
    __builtin_amdgcn_s_setprio(0);

    float linv[2][4];
    f32x4_t oacc[2][4] = {};
#pragma unroll
    for (int mf = 0; mf < 2; ++mf) {
#pragma unroll
      for (int r = 0; r < 4; ++r) {
        float pv[16];
        float sum = 0.f;
#pragma unroll
        for (int nj = 0; nj < 16; ++nj) {
          pv[nj] = __expf(sacc[mf][nj][r] * SCALE_);
          sum += pv[nj];
        }
        sum += __shfl_xor(sum, 1);
        sum += __shfl_xor(sum, 2);
        sum += __shfl_xor(sum, 4);
        sum += __shfl_xor(sum, 8);
        linv[mf][r] = 1.f / sum;
        int q4 = lk * 4 + r;
#pragma unroll
        for (int nj = 0; nj < 16; ++nj)
          *reinterpret_cast<ushort*>(lp + p_byte(wid, q4, nj * 16 + lr)) = f2b(pv[nj]);
      }
      __builtin_amdgcn_s_setprio(1);
#pragma unroll
      for (int ks2 = 0; ks2 < 8; ++ks2) {
        bf16x8 pf = *reinterpret_cast<const bf16x8*>(
            lp + p_byte(wid, lr, ks2 * 32 + lk * 8));
#pragma unroll
        for (int df = 0; df < 4; ++df) {
          bf16x8 vf = *reinterpret_cast<const bf16x8*>(
              lp + vt_byte(df * 16 + lr, ks2 * 32 + lk * 8));
          oacc[mf][df] = __builtin_amdgcn_mfma_f32_16x16x32_bf16(pf, vf, oacc[mf][df], 0, 0, 0);
        }
      }
      __builtin_amdgcn_s_setprio(0);
    }

#pragma unroll
    for (int mf = 0; mf < 2; ++mf)
#pragma unroll
      for (int df = 0; df < 4; ++df)
#pragma unroll
        for (int r = 0; r < 4; ++r) {
          int qrow = qbase + mf * 16 + lk * 4 + r;
          int dcol = df * 16 + lr;
          float val = oacc[mf][df][r] * linv[mf][r];
          attob[((size_t)(b * N_ + qrow)) * DIM_ + h * HD_ + dcol] = f2b(val);
        }
  }
}

// ---------------------------------------------------------------------------
extern "C" void kernel_launch(void* const* d_in, const int* in_sizes, int n_in,
                              void* d_out, int out_size, void* d_ws, size_t ws_size,
                              hipStream_t stream) {
  const float* feats  = (const float*)d_in[0];
  const float* W_q    = (const float*)d_in[1];
  const float* conv_w = (const float*)d_in[2];
  const float* conv_b = (const float*)d_in[3];
  const float* ln_g   = (const float*)d_in[4];
  const float* ln_b   = (const float*)d_in[5];
  const float* W_out  = (const float*)d_in[6];
  float* out = (float*)d_out;

  const size_t FP_ELEMS = (size_t)B_ * PW * PW * DIM_;   // 18.94M
  char* ws = (char*)d_ws;
  ushort* featsp = (ushort*)ws;  ws += FP_ELEMS * 2;                  // 37.9 MB
  ushort* qb     = (ushort*)ws;  ws += (size_t)B_ * N_ * DIM_ * 2;    // 33.5 MB
  ushort* attob  = (ushort*)ws;  ws += (size_t)B_ * N_ * DIM_ * 2;    // 33.5 MB
  float*  kvf    = (float*)ws;   ws += (size_t)B_ * M2 * CDIM * 4;    // 33.5 MB
  ushort* convwb = (ushort*)ws;  ws += (size_t)CDIM * KCONV * 2;      //  9.4 MB
  ushort* wqb    = (ushort*)ws;  ws += (size_t)DIM_ * DIM_ * 2;       //  0.5 MB
  ushort* woutb  = (ushort*)ws;  ws += (size_t)DIM_ * DIM_ * 2;       //  0.5 MB
  ushort* Kb     = (ushort*)ws;  ws += (size_t)B_ * HEAD_ * M2 * HD_ * 2;  // 8.4 MB
  ushort* Vt     = (ushort*)ws;  ws += (size_t)B_ * HEAD_ * M2 * HD_ * 2;  // 8.4 MB
  // conv K-split partial #1 aliased onto attob (f32 33.5 MB; attob is dead
  // until attention, which runs after LN consumes the partial)
  float* kvp1 = (float*)attob;

  // merged prep: halo zero + W_q/W_out casts
  misc_prep_kernel<<<1568, 256, 0, stream>>>(featsp, W_q, wqb, W_out, woutb);
  cast_featsp_kernel<<<16384, 256, 0, stream>>>(feats, featsp);
  permute_convw_kernel<<<dim3(18, CDIM), 256, 0, stream>>>(conv_w, convwb);

  // q = feats @ W_q^T  -> bf16
  qproj_kernel<<<dim3(DIM_ / 128, (B_ * N_) / 128), 256, 0, stream>>>(
      featsp, wqb, qb);

  // kv_pre = conv(feats) + bias: 256^2 tile, 8-phase pipeline, K-split z=2
  conv256_kernel<<<dim3(CDIM / 256, (B_ * M2) / 256, 2), 512, 0, stream>>>(
      featsp, convwb, conv_b, kvf, kvp1);

  // LayerNorm (sums partials) -> Kb (row-major) + Vt (transposed)
  ln_kernel<<<B_ * M2, 256, 0, stream>>>(kvf, kvp1, ln_g, ln_b, Kb, Vt);

  // MFMA attention (one block per bh, single-barrier) -> attob
  attn_mfma_kernel<<<B_ * HEAD_, 512, 0, stream>>>(qb, Kb, Vt, attob);

  // out = attout @ W_out^T
  gemm0_kernel<<<dim3(DIM_ / 128, (B_ * N_) / 128), 256, 0, stream>>>(
      attob, woutb, out, B_ * N_, DIM_, DIM_);
}

// Round 15
// 242.674 us; speedup vs baseline: 1.0759x; 1.0759x over previous
//
#include <hip/hip_runtime.h>
#include <hip/hip_bf16.h>
#include <math.h>

// Problem constants
#define B_    32
#define N_    1024
#define DIM_  512
#define HEAD_ 8
#define HD_   64        // head dim
#define WSP   32        // sqrt(N)
#define M2    256       // kv spatial positions (16*16)
#define CDIM  1024      // 2*DIM
#define KCONV 4608      // DIM*3*3
#define KHALF 2304      // conv K-split chunk
#define EPS_  1e-5f
#define SCALE_ 0.044194173824159216f  // DIM^-0.5
#define PW    34        // padded spatial side (32 + 2 halo)

typedef __attribute__((ext_vector_type(8))) short bf16x8;
typedef __attribute__((ext_vector_type(4))) float f32x4_t;
typedef const __attribute__((address_space(1))) void gas_t;   // global addr space
typedef __attribute__((address_space(3))) void las_t;         // LDS addr space

__device__ __forceinline__ ushort f2b(float x) {
  __hip_bfloat16 h = __float2bfloat16(x);
  return *reinterpret_cast<const ushort*>(&h);
}

// ---------------------------------------------------------------------------
// ONE merged prep dispatch:
//  [0,1056)        zero featsp halo border
//  [1056,1312)     cast W_q -> bf16
//  [1312,1568)     cast W_out -> bf16
//  [1568,20000)    permute+cast conv_w -> convwb [oc][tap*512+ic]
//  [20000,36384)   cast feats -> padded featsp interior
// ---------------------------------------------------------------------------
__global__ __launch_bounds__(256) void prep_kernel(
    const float* __restrict__ feats, ushort* __restrict__ featsp,
    const float* __restrict__ W_q, ushort* __restrict__ wqb,
    const float* __restrict__ W_out, ushort* __restrict__ woutb,
    const float* __restrict__ conv_w, ushort* __restrict__ convwb) {
  int blk = blockIdx.x;
  if (blk < 1056) {
    int t = blk * 256 + threadIdx.x;           // 270336 = 32*8448 exact
    int b = t / 8448, r = t - b * 8448;        // 8448 = 132*64
    int cell = r >> 6, ic8 = (r & 63) * 8;
    int iw, ih;
    if (cell < 34)      { iw = 0;  ih = cell; }
    else if (cell < 68) { iw = 33; ih = cell - 34; }
    else { int e = cell - 68; iw = 1 + (e >> 1); ih = (e & 1) * 33; }
    bf16x8 z = {};
    *reinterpret_cast<bf16x8*>(&featsp[(((size_t)b * PW + iw) * PW + ih) * 512 + ic8]) = z;
  } else if (blk < 1312) {
    int i = (blk - 1056) * 256 + threadIdx.x;  // [0, 65536)
    float4 v = reinterpret_cast<const float4*>(W_q)[i];
    ushort4 o;
    o.x = f2b(v.x); o.y = f2b(v.y); o.z = f2b(v.z); o.w = f2b(v.w);
    reinterpret_cast<ushort4*>(wqb)[i] = o;
  } else if (blk < 1568) {
    int i = (blk - 1312) * 256 + threadIdx.x;
    float4 v = reinterpret_cast<const float4*>(W_out)[i];
    ushort4 o;
    o.x = f2b(v.x); o.y = f2b(v.y); o.z = f2b(v.z); o.w = f2b(v.w);
    reinterpret_cast<ushort4*>(woutb)[i] = o;
  } else if (blk < 20000) {
    int t2 = blk - 1568;                       // 18432 blocks = 1024 oc x 18
    int oc = t2 / 18, sub = t2 - oc * 18;
    int idx = sub * 256 + threadIdx.x;         // [0, 4608)
    int tap = idx >> 9, ic = idx & 511;
    convwb[(size_t)oc * KCONV + idx] = f2b(conv_w[(size_t)oc * KCONV + ic * 9 + tap]);
  } else {
    int i = (blk - 20000) * 256 + threadIdx.x; // ushort4 index, 4.19M
    int e = i * 4;
    int b = e >> 19, r = e & 524287;
    int n = r >> 9, ic = r & 511;
    int iw = n >> 5, ih = n & 31;
    float4 v = reinterpret_cast<const float4*>(feats)[i];
    ushort4 o;
    o.x = f2b(v.x); o.y = f2b(v.y); o.z = f2b(v.z); o.w = f2b(v.w);
    size_t dst = (((size_t)b * PW + iw + 1) * PW + ih + 1) * 512 + ic;
    *reinterpret_cast<ushort4*>(&featsp[dst]) = o;
  }
}

// ---------------------------------------------------------------------------
// conv 256x256 tile, BK=64, 8 waves (R13 best config): LDS double-buffer
// 2x64KB, global_load_lds(16B) w/ source chunk-swizzle (ch ^= row&7),
// counted-vmcnt 2-phase loop, XCD swizzle, K-split z=2.
// z==0 writes kvf (+bias), z==1 writes kvp1; LN sums.
// ---------------------------------------------------------------------------
__global__ __launch_bounds__(512, 2) void conv256_kernel(
    const ushort* __restrict__ featsp, const ushort* __restrict__ convwb,
    const float* __restrict__ conv_b, float* __restrict__ kvf,
    float* __restrict__ kvp1) {
  __shared__ __align__(16) ushort lds[2][32768];   // 2 x 64 KB
  const int tid = threadIdx.x;                 // 0..511
  const int lane = tid & 63, wid = tid >> 6;   // 8 waves
  const int wr = wid >> 2, wc = wid & 3;       // 2M x 4N
  const int lrow = lane & 15, lk = lane >> 4;
  const int kz = blockIdx.z;
  const int koff = kz * KHALF;

  // XCD swizzle within z-slice (nwg=128, %8==0 -> bijective)
  const int l = blockIdx.y * gridDim.x + blockIdx.x;   // 0..127
  const int v = (l & 7) * 16 + (l >> 3);
  const int bm = (v >> 2) * 256;               // nbn = 4
  const int bn = (v & 3) * 256;
  const int bimg = bm >> 8;                    // one image per bm-tile

  f32x4_t acc[8][4] = {};

  auto stage = [&](int buf, int kt) {
    int k0 = koff + (kt << 6);
#pragma unroll
    for (int i = 0; i < 4; ++i) {
      int s = i * 512 + tid;
      int row = s >> 3, ch = s & 7;
      int cl = ch ^ (row & 7);                 // logical chunk (involution)
      int kk = k0 + cl * 8;
      int tap = kk >> 9, ic = kk & 511;
      int kh = tap / 3, kw = tap - 3 * kh;
      int w2 = row >> 4, h2 = row & 15;
      const ushort* ga = &featsp[(((size_t)bimg * PW + 2 * w2 + kh) * PW + 2 * h2 + kw) * 512 + ic];
      __builtin_amdgcn_global_load_lds((gas_t*)ga,
          (las_t*)(&lds[buf][0] + (size_t)s * 8), 16, 0, 0);
    }
#pragma unroll
    for (int i = 0; i < 4; ++i) {
      int s = i * 512 + tid;
      int row = s >> 3, ch = s & 7;
      int cl = ch ^ (row & 7);
      const ushort* gb = &convwb[(size_t)(bn + row) * KCONV + k0 + cl * 8];
      __builtin_amdgcn_global_load_lds((gas_t*)gb,
          (las_t*)(&lds[buf][16384] + (size_t)s * 8), 16, 0, 0);
    }
  };

  const int NT = KHALF >> 6;                   // 36
  stage(0, 0);
  for (int kt = 0; kt < NT; ++kt) {
    int cur = kt & 1;
    if (kt + 1 < NT) {
      stage(cur ^ 1, kt + 1);                  // 16 in flight
      asm volatile("s_waitcnt vmcnt(8)" ::: "memory");   // cur's 8 retired
    } else {
      asm volatile("s_waitcnt vmcnt(0)" ::: "memory");
    }
    __builtin_amdgcn_s_barrier();
    __builtin_amdgcn_sched_barrier(0);
#pragma unroll
    for (int kk = 0; kk < 2; ++kk) {
      bf16x8 aF[8], bF[4];
#pragma unroll
      for (int m = 0; m < 8; ++m) {
        int row = wr * 128 + m * 16 + lrow;
        int ch = (kk * 4 + lk) ^ (row & 7);
        aF[m] = *reinterpret_cast<const bf16x8*>(&lds[cur][row * 64 + ch * 8]);
      }
#pragma unroll
      for (int n = 0; n < 4; ++n) {
        int row = wc * 64 + n * 16 + lrow;
        int ch = (kk * 4 + lk) ^ (row & 7);
        bF[n] = *reinterpret_cast<const bf16x8*>(&lds[cur][16384 + row * 64 + ch * 8]);
      }
#pragma unroll
      for (int m = 0; m < 8; ++m)
#pragma unroll
        for (int n = 0; n < 4; ++n)
          acc[m][n] = __builtin_amdgcn_mfma_f32_16x16x32_bf16(
              aF[m], bF[n], acc[m][n], 0, 0, 0);
    }
    __builtin_amdgcn_sched_barrier(0);
    __builtin_amdgcn_s_barrier();
  }

  float* Co = kz ? kvp1 : kvf;
#pragma unroll
  for (int m = 0; m < 8; ++m) {
#pragma unroll
    for (int n = 0; n < 4; ++n) {
      int col = bn + wc * 64 + n * 16 + lrow;
#pragma unroll
      for (int r = 0; r < 4; ++r) {
        int row = bm + wr * 128 + m * 16 + lk * 4 + r;
        float v2 = acc[m][n][r];
        if (kz == 0) v2 += conv_b[col];
        Co[(size_t)row * CDIM + col] = v2;
      }
    }
  }
}

// ---------------------------------------------------------------------------
// Shared MFMA GEMM body (R10/R12 config) for q-proj and out-proj.
// ---------------------------------------------------------------------------
template<int MODE>
__device__ __forceinline__ void gemm_body(
    ushort (*As)[128][32], ushort (*Bs)[128][32],
    int l, int nbn, int nwg,
    const ushort* __restrict__ A, const ushort* __restrict__ featsp,
    const ushort* __restrict__ Bw, float* __restrict__ Cf,
    ushort* __restrict__ Cb, int M, int N, int K) {
  const int tid = threadIdx.x;
  const int lane = tid & 63, wid = tid >> 6;
  const int wr = wid >> 1, wc = wid & 1;
  const int v = (l & 7) * (nwg >> 3) + (l >> 3);
  const int bm = (v / nbn) * 128, bn = (v % nbn) * 128;
  const int lrow = lane & 15, lk = lane >> 4;
  const int swz = (lrow >> 1) & 3;

  f32x4_t acc[4][4] = {};

  auto stage = [&](int buf, int kt) {
    int k0 = kt << 5;
#pragma unroll
    for (int it = 0; it < 2; ++it) {
      int idx = it * 256 + tid;
      int row = idx >> 2;
      int c = (((idx & 3) ^ ((idx >> 3) & 3))) * 8;
      const ushort* ga;
      if (MODE == 0) {
        ga = &A[(size_t)(bm + row) * K + k0 + c];
      } else {
        int p = bm + row;
        int b = p >> 10, n = p & 1023;
        int iw = n >> 5, ih = n & 31;
        ga = &featsp[(((size_t)b * PW + iw + 1) * PW + ih + 1) * 512 + k0 + c];
      }
      __builtin_amdgcn_global_load_lds((gas_t*)ga,
          (las_t*)(&As[buf][0][0] + (size_t)idx * 8), 16, 0, 0);
      const ushort* gb = &Bw[(size_t)(bn + row) * K + k0 + c];
      __builtin_amdgcn_global_load_lds((gas_t*)gb,
          (las_t*)(&Bs[buf][0][0] + (size_t)idx * 8), 16, 0, 0);
    }
  };

  stage(0, 0);
  const int NT = K >> 5;
  for (int kt = 0; kt < NT; ++kt) {
    int cur = kt & 1;
    if (kt + 1 < NT) {
      stage(cur ^ 1, kt + 1);
      asm volatile("s_waitcnt vmcnt(4)" ::: "memory");
    } else {
      asm volatile("s_waitcnt vmcnt(0)" ::: "memory");
    }
    __builtin_amdgcn_s_barrier();
    __builtin_amdgcn_sched_barrier(0);
    bf16x8 aF[4], bF[4];
#pragma unroll
    for (int m = 0; m < 4; ++m)
      aF[m] = *reinterpret_cast<const bf16x8*>(
          &As[cur][wr * 64 + m * 16 + lrow][(lk ^ swz) * 8]);
#pragma unroll
    for (int n = 0; n < 4; ++n)
      bF[n] = *reinterpret_cast<const bf16x8*>(
          &Bs[cur][wc * 64 + n * 16 + lrow][(lk ^ swz) * 8]);
#pragma unroll
    for (int m = 0; m < 4; ++m)
#pragma unroll
      for (int n = 0; n < 4; ++n)
        acc[m][n] = __builtin_amdgcn_mfma_f32_16x16x32_bf16(
            aF[m], bF[n], acc[m][n], 0, 0, 0);
    __builtin_amdgcn_sched_barrier(0);
    __builtin_amdgcn_s_barrier();
  }

#pragma unroll
  for (int m = 0; m < 4; ++m) {
#pragma unroll
    for (int n = 0; n < 4; ++n) {
      int col = bn + wc * 64 + n * 16 + lrow;
#pragma unroll
      for (int r = 0; r < 4; ++r) {
        int row = bm + wr * 64 + m * 16 + lk * 4 + r;
        float v2 = acc[m][n][r];
        if (MODE == 1) Cb[(size_t)row * N + col] = f2b(v2);
        else Cf[(size_t)row * N + col] = v2;
      }
    }
  }
}

// q-proj (MODE 1)
__global__ __launch_bounds__(256) void qproj_kernel(
    const ushort* __restrict__ featsp, const ushort* __restrict__ wqb,
    ushort* __restrict__ qb) {
  __shared__ ushort As[2][128][32];
  __shared__ ushort Bs[2][128][32];
  int l = blockIdx.y * gridDim.x + blockIdx.x;
  gemm_body<1>(As, Bs, l, gridDim.x, gridDim.x * gridDim.y,
               nullptr, featsp, wqb, nullptr, qb, B_ * N_, DIM_, DIM_);
}

// out-proj (MODE 0)
__global__ __launch_bounds__(256) void gemm0_kernel(
    const ushort* __restrict__ A, const ushort* __restrict__ Bw,
    float* __restrict__ Cf, int M, int N, int K) {
  __shared__ ushort As[2][128][32];
  __shared__ ushort Bs[2][128][32];
  int l = blockIdx.y * gridDim.x + blockIdx.x;
  gemm_body<0>(As, Bs, l, gridDim.x, gridDim.x * gridDim.y,
               A, nullptr, Bw, Cf, nullptr, M, N, K);
}

// ---------------------------------------------------------------------------
// LayerNorm over last dim (1024) of conv partials p0+p1 (f32).
// K half -> Kb[bh][256][64] row-major; V half -> Vb[bh][256][64] row-major
// (BOTH coalesced ushort4; the V transpose moved to vtrans_kernel).
// ---------------------------------------------------------------------------
__global__ __launch_bounds__(256) void ln_kernel(
    const float* __restrict__ kvp0, const float* __restrict__ kvp1,
    const float* __restrict__ gamma, const float* __restrict__ beta,
    ushort* __restrict__ Kb, ushort* __restrict__ Vb) {
  const int p = blockIdx.x, tid = threadIdx.x;
  float4 a = reinterpret_cast<const float4*>(kvp0 + (size_t)p * CDIM)[tid];
  float4 b4 = reinterpret_cast<const float4*>(kvp1 + (size_t)p * CDIM)[tid];
  float4 x = make_float4(a.x + b4.x, a.y + b4.y, a.z + b4.z, a.w + b4.w);
  float s = x.x + x.y + x.z + x.w;
  float ss = x.x * x.x + x.y * x.y + x.z * x.z + x.w * x.w;
#pragma unroll
  for (int off = 32; off > 0; off >>= 1) {
    s += __shfl_down(s, off);
    ss += __shfl_down(ss, off);
  }
  __shared__ float sb[4], ssb[4];
  if ((tid & 63) == 0) { sb[tid >> 6] = s; ssb[tid >> 6] = ss; }
  __syncthreads();
  float tot = sb[0] + sb[1] + sb[2] + sb[3];
  float tot2 = ssb[0] + ssb[1] + ssb[2] + ssb[3];
  float mu = tot * (1.f / CDIM);
  float var = tot2 * (1.f / CDIM) - mu * mu;
  float rstd = rsqrtf(var + EPS_);
  float4 g = reinterpret_cast<const float4*>(gamma)[tid];
  float4 bb = reinterpret_cast<const float4*>(beta)[tid];
  ushort4 o;
  o.x = f2b((x.x - mu) * rstd * g.x + bb.x);
  o.y = f2b((x.y - mu) * rstd * g.y + bb.y);
  o.z = f2b((x.z - mu) * rstd * g.z + bb.z);
  o.w = f2b((x.w - mu) * rstd * g.w + bb.w);
  int b = p >> 8, j = p & 255;
  int c = tid * 4;
  if (c < DIM_) {
    int h = c >> 6, d = c & 63;
    *reinterpret_cast<ushort4*>(&Kb[(((size_t)(b * 8 + h)) * M2 + j) * HD_ + d]) = o;
  } else {
    int c2 = c - DIM_;
    int h = c2 >> 6, d = c2 & 63;
    *reinterpret_cast<ushort4*>(&Vb[(((size_t)(b * 8 + h)) * M2 + j) * HD_ + d]) = o;
  }
}

// ---------------------------------------------------------------------------
// V transpose: Vb[bh][256 j][64 d] -> Vt[bh][64 d][256 j] via LDS 64x65
// padded tiles. One block per bh, 256 threads, 4 j-chunks. Coalesced both
// global sides; LDS conflicts <= 4-way on a ~3 us kernel.
// ---------------------------------------------------------------------------
__global__ __launch_bounds__(256) void vtrans_kernel(
    const ushort* __restrict__ Vb, ushort* __restrict__ Vt) {
  __shared__ ushort t[64][65];
  const int bh = blockIdx.x, tid = threadIdx.x;
  const ushort* src = Vb + (size_t)bh * M2 * HD_;
  ushort* dst = Vt + (size_t)bh * HD_ * M2;
  for (int j0 = 0; j0 < M2; j0 += 64) {
    __syncthreads();                     // guard previous tile's reads
#pragma unroll
    for (int it = 0; it < 2; ++it) {
      int s = it * 256 + tid;            // 0..511
      int j = s >> 3, d0 = (s & 7) * 8;
      bf16x8 v = *reinterpret_cast<const bf16x8*>(src + (size_t)(j0 + j) * HD_ + d0);
#pragma unroll
      for (int e = 0; e < 8; ++e) t[d0 + e][j] = (ushort)v[e];
    }
    __syncthreads();
#pragma unroll
    for (int it = 0; it < 2; ++it) {
      int s = it * 256 + tid;
      int d = s >> 3, jj0 = (s & 7) * 8;
      bf16x8 o;
#pragma unroll
      for (int e = 0; e < 8; ++e) o[e] = (short)t[d][jj0 + e];
      *reinterpret_cast<bf16x8*>(dst + (size_t)d * M2 + j0 + jj0) = o;
    }
  }
}

// ---------------------------------------------------------------------------
// MFMA attention (R12): ONE block per (b,h), 512 threads = 8 waves, K/V
// staged once, single barrier, per-wave private P. LDS 128 KiB.
// ---------------------------------------------------------------------------
__global__ __launch_bounds__(512, 2) void attn_mfma_kernel(
    const ushort* __restrict__ qb, const ushort* __restrict__ Kb,
    const ushort* __restrict__ Vt, ushort* __restrict__ attob) {
  __shared__ __align__(16) char lds[131072];
  char* lp = lds;
  const int tid = threadIdx.x;
  const int lane = tid & 63, wid = tid >> 6;   // wid 0..7
  const int lr = lane & 15, lk = lane >> 4;
  const int bh = blockIdx.x;
  const int b = bh >> 3, h = bh & 7;

  auto ks_byte = [](int j, int d) -> int {            // K[256][64] @0
    return (j << 7) + (((d << 1)) ^ ((j & 7) << 4));
  };
  auto vt_byte = [](int d, int j) -> int {            // V^T[64][256] @32K
    return 32768 + (d << 9) + (((j << 1)) ^ ((d & 7) << 4));
  };
  auto p_byte = [](int w, int q4, int kv) -> int {    // P per wave @64K
    return 65536 + (w << 13) + (q4 << 9) + (((kv << 1)) ^ ((q4 & 7) << 4));
  };

  const ushort* Khead  = Kb + (size_t)bh * M2 * HD_;   // [256][64]
  const ushort* Vthead = Vt + (size_t)bh * HD_ * M2;   // [64][256]

#pragma unroll
  for (int it = 0; it < 4; ++it) {
    int o = (it * 512 + tid) * 16;
    int j = o >> 7, c = (o >> 4) & 7;
    int cl = c ^ (j & 7);
    __builtin_amdgcn_global_load_lds((gas_t*)(Khead + j * HD_ + cl * 8),
        (las_t*)(lp + o), 16, 0, 0);
  }
#pragma unroll
  for (int it = 0; it < 4; ++it) {
    int o = (it * 512 + tid) * 16;
    int d = o >> 9, c = (o >> 4) & 31;
    int cl = c ^ (d & 7);
    __builtin_amdgcn_global_load_lds((gas_t*)(Vthead + d * M2 + cl * 8),
        (las_t*)(lp + 32768 + o), 16, 0, 0);
  }

  __syncthreads();   // the ONLY block-wide barrier

  for (int qp = 0; qp < 4; ++qp) {
    const int qbase = qp * 256 + wid * 32;
    bf16x8 qf[2][2];
#pragma unroll
    for (int mf = 0; mf < 2; ++mf)
#pragma unroll
      for (int ks = 0; ks < 2; ++ks)
        qf[mf][ks] = *reinterpret_cast<const bf16x8*>(
            qb + ((size_t)(b * N_ + qbase + mf * 16 + lr)) * DIM_ + h * HD_ + ks * 32 + lk * 8);

    f32x4_t sacc[2][16] = {};
    __builtin_amdgcn_s_setprio(1);
#pragma unroll
    for (int ks = 0; ks < 2; ++ks) {
#pragma unroll
      for (int nj = 0; nj < 16; ++nj) {
        bf16x8 kf = *reinterpret_cast<const bf16x8*>(
            lp + ks_byte(nj * 16 + lr, ks * 32 + lk * 8));
        sacc[0][nj] = __builtin_amdgcn_mfma_f32_16x16x32_bf16(qf[0][ks], kf, sacc[0][nj], 0, 0, 0);
        sacc[1][nj] = __builtin_amdgcn_mfma_f32_16x16x32_bf16(qf[1][ks], kf, sacc[1][nj], 0, 0, 0);
      }
    }
    __builtin_amdgcn_s_setprio(0);

    float linv[2][4];
    f32x4_t oacc[2][4] = {};
#pragma unroll
    for (int mf = 0; mf < 2; ++mf) {
#pragma unroll
      for (int r = 0; r < 4; ++r) {
        float pv[16];
        float sum = 0.f;
#pragma unroll
        for (int nj = 0; nj < 16; ++nj) {
          pv[nj] = __expf(sacc[mf][nj][r] * SCALE_);
          sum += pv[nj];
        }
        sum += __shfl_xor(sum, 1);
        sum += __shfl_xor(sum, 2);
        sum += __shfl_xor(sum, 4);
        sum += __shfl_xor(sum, 8);
        linv[mf][r] = 1.f / sum;
        int q4 = lk * 4 + r;
#pragma unroll
        for (int nj = 0; nj < 16; ++nj)
          *reinterpret_cast<ushort*>(lp + p_byte(wid, q4, nj * 16 + lr)) = f2b(pv[nj]);
      }
      __builtin_amdgcn_s_setprio(1);
#pragma unroll
      for (int ks2 = 0; ks2 < 8; ++ks2) {
        bf16x8 pf = *reinterpret_cast<const bf16x8*>(
            lp + p_byte(wid, lr, ks2 * 32 + lk * 8));
#pragma unroll
        for (int df = 0; df < 4; ++df) {
          bf16x8 vf = *reinterpret_cast<const bf16x8*>(
              lp + vt_byte(df * 16 + lr, ks2 * 32 + lk * 8));
          oacc[mf][df] = __builtin_amdgcn_mfma_f32_16x16x32_bf16(pf, vf, oacc[mf][df], 0, 0, 0);
        }
      }
      __builtin_amdgcn_s_setprio(0);
    }

#pragma unroll
    for (int mf = 0; mf < 2; ++mf)
#pragma unroll
      for (int df = 0; df < 4; ++df)
#pragma unroll
        for (int r = 0; r < 4; ++r) {
          int qrow = qbase + mf * 16 + lk * 4 + r;
          int dcol = df * 16 + lr;
          float val = oacc[mf][df][r] * linv[mf][r];
          attob[((size_t)(b * N_ + qrow)) * DIM_ + h * HD_ + dcol] = f2b(val);
        }
  }
}

// ---------------------------------------------------------------------------
extern "C" void kernel_launch(void* const* d_in, const int* in_sizes, int n_in,
                              void* d_out, int out_size, void* d_ws, size_t ws_size,
                              hipStream_t stream) {
  const float* feats  = (const float*)d_in[0];
  const float* W_q    = (const float*)d_in[1];
  const float* conv_w = (const float*)d_in[2];
  const float* conv_b = (const float*)d_in[3];
  const float* ln_g   = (const float*)d_in[4];
  const float* ln_b   = (const float*)d_in[5];
  const float* W_out  = (const float*)d_in[6];
  float* out = (float*)d_out;

  const size_t FP_ELEMS = (size_t)B_ * PW * PW * DIM_;   // 18.94M
  char* ws = (char*)d_ws;
  ushort* featsp = (ushort*)ws;  ws += FP_ELEMS * 2;                  // 37.9 MB
  ushort* qb     = (ushort*)ws;  ws += (size_t)B_ * N_ * DIM_ * 2;    // 33.5 MB
  ushort* attob  = (ushort*)ws;  ws += (size_t)B_ * N_ * DIM_ * 2;    // 33.5 MB
  float*  kvf    = (float*)ws;   ws += (size_t)B_ * M2 * CDIM * 4;    // 33.5 MB
  ushort* convwb = (ushort*)ws;  ws += (size_t)CDIM * KCONV * 2;      //  9.4 MB
  ushort* wqb    = (ushort*)ws;  ws += (size_t)DIM_ * DIM_ * 2;       //  0.5 MB
  ushort* woutb  = (ushort*)ws;  ws += (size_t)DIM_ * DIM_ * 2;       //  0.5 MB
  ushort* Kb     = (ushort*)ws;  ws += (size_t)B_ * HEAD_ * M2 * HD_ * 2;  // 8.4 MB
  ushort* Vt     = (ushort*)ws;  ws += (size_t)B_ * HEAD_ * M2 * HD_ * 2;  // 8.4 MB
  // conv K-split partial #1 aliased onto attob (dead until attention)
  float* kvp1 = (float*)attob;
  // Vb (row-major V) aliased onto convwb (dead after conv256)
  ushort* Vb = convwb;

  // ONE merged prep dispatch (border + feats cast + convw permute + W casts)
  prep_kernel<<<36384, 256, 0, stream>>>(
      feats, featsp, W_q, wqb, W_out, woutb, conv_w, convwb);

  // q = feats @ W_q^T  -> bf16
  qproj_kernel<<<dim3(DIM_ / 128, (B_ * N_) / 128), 256, 0, stream>>>(
      featsp, wqb, qb);

  // kv_pre = conv(feats) + bias: 256^2 tile, K-split z=2 (R13 schedule)
  conv256_kernel<<<dim3(CDIM / 256, (B_ * M2) / 256, 2), 512, 0, stream>>>(
      featsp, convwb, conv_b, kvf, kvp1);

  // LayerNorm (sums partials) -> Kb + Vb (both row-major, coalesced)
  ln_kernel<<<B_ * M2, 256, 0, stream>>>(kvf, kvp1, ln_g, ln_b, Kb, Vb);

  // V transpose: Vb -> Vt (LDS-tiled, coalesced)
  vtrans_kernel<<<B_ * HEAD_, 256, 0, stream>>>(Vb, Vt);

  // MFMA attention (one block per bh, single-barrier) -> attob
  attn_mfma_kernel<<<B_ * HEAD_, 512, 0, stream>>>(qb, Kb, Vt, attob);

  // out = attout @ W_out^T
  gemm0_kernel<<<dim3(DIM_ / 128, (B_ * N_) / 128), 256, 0, stream>>>(
      attob, woutb, out, B_ * N_, DIM_, DIM_);
}

// Round 16
// 232.475 us; speedup vs baseline: 1.1231x; 1.0439x over previous
//
#include <hip/hip_runtime.h>
#include <hip/hip_bf16.h>
#include <math.h>

// Problem constants
#define B_    32
#define N_    1024
#define DIM_  512
#define HEAD_ 8
#define HD_   64        // head dim
#define WSP   32        // sqrt(N)
#define M2    256       // kv spatial positions (16*16)
#define CDIM  1024      // 2*DIM
#define KCONV 4608      // DIM*3*3
#define KHALF 2304      // conv K-split chunk
#define EPS_  1e-5f
#define SCALE_ 0.044194173824159216f  // DIM^-0.5
#define PW    34        // padded spatial side (32 + 2 halo)

typedef __attribute__((ext_vector_type(8))) short bf16x8;
typedef __attribute__((ext_vector_type(4))) float f32x4_t;
typedef const __attribute__((address_space(1))) void gas_t;   // global addr space
typedef __attribute__((address_space(3))) void las_t;         // LDS addr space

__device__ __forceinline__ ushort f2b(float x) {
  __hip_bfloat16 h = __float2bfloat16(x);
  return *reinterpret_cast<const ushort*>(&h);
}

// ---------------------------------------------------------------------------
// ONE merged prep dispatch:
//  [0,1056)        zero featsp halo border
//  [1056,1312)     cast W_q -> bf16
//  [1312,1568)     cast W_out -> bf16
//  [1568,20000)    permute+cast conv_w -> convwb [oc][tap*512+ic]
//  [20000,36384)   cast feats -> padded featsp interior
// ---------------------------------------------------------------------------
__global__ __launch_bounds__(256) void prep_kernel(
    const float* __restrict__ feats, ushort* __restrict__ featsp,
    const float* __restrict__ W_q, ushort* __restrict__ wqb,
    const float* __restrict__ W_out, ushort* __restrict__ woutb,
    const float* __restrict__ conv_w, ushort* __restrict__ convwb) {
  int blk = blockIdx.x;
  if (blk < 1056) {
    int t = blk * 256 + threadIdx.x;           // 270336 = 32*8448 exact
    int b = t / 8448, r = t - b * 8448;        // 8448 = 132*64
    int cell = r >> 6, ic8 = (r & 63) * 8;
    int iw, ih;
    if (cell < 34)      { iw = 0;  ih = cell; }
    else if (cell < 68) { iw = 33; ih = cell - 34; }
    else { int e = cell - 68; iw = 1 + (e >> 1); ih = (e & 1) * 33; }
    bf16x8 z = {};
    *reinterpret_cast<bf16x8*>(&featsp[(((size_t)b * PW + iw) * PW + ih) * 512 + ic8]) = z;
  } else if (blk < 1312) {
    int i = (blk - 1056) * 256 + threadIdx.x;  // [0, 65536)
    float4 v = reinterpret_cast<const float4*>(W_q)[i];
    ushort4 o;
    o.x = f2b(v.x); o.y = f2b(v.y); o.z = f2b(v.z); o.w = f2b(v.w);
    reinterpret_cast<ushort4*>(wqb)[i] = o;
  } else if (blk < 1568) {
    int i = (blk - 1312) * 256 + threadIdx.x;
    float4 v = reinterpret_cast<const float4*>(W_out)[i];
    ushort4 o;
    o.x = f2b(v.x); o.y = f2b(v.y); o.z = f2b(v.z); o.w = f2b(v.w);
    reinterpret_cast<ushort4*>(woutb)[i] = o;
  } else if (blk < 20000) {
    int t2 = blk - 1568;                       // 18432 blocks = 1024 oc x 18
    int oc = t2 / 18, sub = t2 - oc * 18;
    int idx = sub * 256 + threadIdx.x;         // [0, 4608)
    int tap = idx >> 9, ic = idx & 511;
    convwb[(size_t)oc * KCONV + idx] = f2b(conv_w[(size_t)oc * KCONV + ic * 9 + tap]);
  } else {
    int i = (blk - 20000) * 256 + threadIdx.x; // ushort4 index, 4.19M
    int e = i * 4;
    int b = e >> 19, r = e & 524287;
    int n = r >> 9, ic = r & 511;
    int iw = n >> 5, ih = n & 31;
    float4 v = reinterpret_cast<const float4*>(feats)[i];
    ushort4 o;
    o.x = f2b(v.x); o.y = f2b(v.y); o.z = f2b(v.z); o.w = f2b(v.w);
    size_t dst = (((size_t)b * PW + iw + 1) * PW + ih + 1) * 512 + ic;
    *reinterpret_cast<ushort4*>(&featsp[dst]) = o;
  }
}

// ---------------------------------------------------------------------------
// conv 256x256 tile, BK=64, 8 waves (R13 best config): LDS double-buffer
// 2x64KB, global_load_lds(16B) w/ source chunk-swizzle (ch ^= row&7),
// counted-vmcnt 2-phase loop, XCD swizzle, K-split z=2.
// z==0 writes kvf (+bias), z==1 writes kvp1; LN sums.
// ---------------------------------------------------------------------------
__global__ __launch_bounds__(512, 2) void conv256_kernel(
    const ushort* __restrict__ featsp, const ushort* __restrict__ convwb,
    const float* __restrict__ conv_b, float* __restrict__ kvf,
    float* __restrict__ kvp1) {
  __shared__ __align__(16) ushort lds[2][32768];   // 2 x 64 KB
  const int tid = threadIdx.x;                 // 0..511
  const int lane = tid & 63, wid = tid >> 6;   // 8 waves
  const int wr = wid >> 2, wc = wid & 3;       // 2M x 4N
  const int lrow = lane & 15, lk = lane >> 4;
  const int kz = blockIdx.z;
  const int koff = kz * KHALF;

  // XCD swizzle within z-slice (nwg=128, %8==0 -> bijective)
  const int l = blockIdx.y * gridDim.x + blockIdx.x;   // 0..127
  const int v = (l & 7) * 16 + (l >> 3);
  const int bm = (v >> 2) * 256;               // nbn = 4
  const int bn = (v & 3) * 256;
  const int bimg = bm >> 8;                    // one image per bm-tile

  f32x4_t acc[8][4] = {};

  auto stage = [&](int buf, int kt) {
    int k0 = koff + (kt << 6);
#pragma unroll
    for (int i = 0; i < 4; ++i) {
      int s = i * 512 + tid;
      int row = s >> 3, ch = s & 7;
      int cl = ch ^ (row & 7);                 // logical chunk (involution)
      int kk = k0 + cl * 8;
      int tap = kk >> 9, ic = kk & 511;
      int kh = tap / 3, kw = tap - 3 * kh;
      int w2 = row >> 4, h2 = row & 15;
      const ushort* ga = &featsp[(((size_t)bimg * PW + 2 * w2 + kh) * PW + 2 * h2 + kw) * 512 + ic];
      __builtin_amdgcn_global_load_lds((gas_t*)ga,
          (las_t*)(&lds[buf][0] + (size_t)s * 8), 16, 0, 0);
    }
#pragma unroll
    for (int i = 0; i < 4; ++i) {
      int s = i * 512 + tid;
      int row = s >> 3, ch = s & 7;
      int cl = ch ^ (row & 7);
      const ushort* gb = &convwb[(size_t)(bn + row) * KCONV + k0 + cl * 8];
      __builtin_amdgcn_global_load_lds((gas_t*)gb,
          (las_t*)(&lds[buf][16384] + (size_t)s * 8), 16, 0, 0);
    }
  };

  const int NT = KHALF >> 6;                   // 36
  stage(0, 0);
  for (int kt = 0; kt < NT; ++kt) {
    int cur = kt & 1;
    if (kt + 1 < NT) {
      stage(cur ^ 1, kt + 1);                  // 16 in flight
      asm volatile("s_waitcnt vmcnt(8)" ::: "memory");   // cur's 8 retired
    } else {
      asm volatile("s_waitcnt vmcnt(0)" ::: "memory");
    }
    __builtin_amdgcn_s_barrier();
    __builtin_amdgcn_sched_barrier(0);
#pragma unroll
    for (int kk = 0; kk < 2; ++kk) {
      bf16x8 aF[8], bF[4];
#pragma unroll
      for (int m = 0; m < 8; ++m) {
        int row = wr * 128 + m * 16 + lrow;
        int ch = (kk * 4 + lk) ^ (row & 7);
        aF[m] = *reinterpret_cast<const bf16x8*>(&lds[cur][row * 64 + ch * 8]);
      }
#pragma unroll
      for (int n = 0; n < 4; ++n) {
        int row = wc * 64 + n * 16 + lrow;
        int ch = (kk * 4 + lk) ^ (row & 7);
        bF[n] = *reinterpret_cast<const bf16x8*>(&lds[cur][16384 + row * 64 + ch * 8]);
      }
#pragma unroll
      for (int m = 0; m < 8; ++m)
#pragma unroll
        for (int n = 0; n < 4; ++n)
          acc[m][n] = __builtin_amdgcn_mfma_f32_16x16x32_bf16(
              aF[m], bF[n], acc[m][n], 0, 0, 0);
    }
    __builtin_amdgcn_sched_barrier(0);
    __builtin_amdgcn_s_barrier();
  }

  float* Co = kz ? kvp1 : kvf;
#pragma unroll
  for (int m = 0; m < 8; ++m) {
#pragma unroll
    for (int n = 0; n < 4; ++n) {
      int col = bn + wc * 64 + n * 16 + lrow;
#pragma unroll
      for (int r = 0; r < 4; ++r) {
        int row = bm + wr * 128 + m * 16 + lk * 4 + r;
        float v2 = acc[m][n][r];
        if (kz == 0) v2 += conv_b[col];
        Co[(size_t)row * CDIM + col] = v2;
      }
    }
  }
}

// ---------------------------------------------------------------------------
// 256x256-tile GEMM for the projections (same engine as conv256, no K-split):
// C[M=32768 x 512] = A[32768 x 512] * B[512 x 512]^T, BK=64, 8 waves,
// counted vmcnt(8), source chunk-swizzle. Grid 2 x 128 = 256 blocks (1/CU).
// MODE 0: A = attob (plain bf16)            -> C f32 (out-proj)
// MODE 1: A = padded-feats center-tap rows  -> C bf16 (q-proj)
// ---------------------------------------------------------------------------
template<int MODE>
__global__ __launch_bounds__(512, 2) void gemm256_kernel(
    const ushort* __restrict__ A, const ushort* __restrict__ featsp,
    const ushort* __restrict__ Bw, float* __restrict__ Cf,
    ushort* __restrict__ Cb) {
  __shared__ __align__(16) ushort lds[2][32768];   // 2 x 64 KB
  const int tid = threadIdx.x;
  const int lane = tid & 63, wid = tid >> 6;
  const int wr = wid >> 2, wc = wid & 3;       // 2M x 4N
  const int lrow = lane & 15, lk = lane >> 4;

  // XCD swizzle (nwg=256, %8==0 -> bijective); nbn=2
  const int l = blockIdx.y * gridDim.x + blockIdx.x;   // 0..255
  const int v = (l & 7) * 32 + (l >> 3);
  const int bm = (v >> 1) * 256;
  const int bn = (v & 1) * 256;

  f32x4_t acc[8][4] = {};

  auto stage = [&](int buf, int kt) {
    int k0 = kt << 6;
#pragma unroll
    for (int i = 0; i < 4; ++i) {
      int s = i * 512 + tid;
      int row = s >> 3, ch = s & 7;
      int cl = ch ^ (row & 7);                 // logical chunk (involution)
      const ushort* ga;
      if (MODE == 1) {
        int p = bm + row;
        int b = p >> 10, n = p & 1023;
        int iw = n >> 5, ih = n & 31;
        ga = &featsp[(((size_t)b * PW + iw + 1) * PW + ih + 1) * 512 + k0 + cl * 8];
      } else {
        ga = &A[(size_t)(bm + row) * DIM_ + k0 + cl * 8];
      }
      __builtin_amdgcn_global_load_lds((gas_t*)ga,
          (las_t*)(&lds[buf][0] + (size_t)s * 8), 16, 0, 0);
    }
#pragma unroll
    for (int i = 0; i < 4; ++i) {
      int s = i * 512 + tid;
      int row = s >> 3, ch = s & 7;
      int cl = ch ^ (row & 7);
      const ushort* gb = &Bw[(size_t)(bn + row) * DIM_ + k0 + cl * 8];
      __builtin_amdgcn_global_load_lds((gas_t*)gb,
          (las_t*)(&lds[buf][16384] + (size_t)s * 8), 16, 0, 0);
    }
  };

  const int NT = DIM_ >> 6;                    // 8
  stage(0, 0);
  for (int kt = 0; kt < NT; ++kt) {
    int cur = kt & 1;
    if (kt + 1 < NT) {
      stage(cur ^ 1, kt + 1);
      asm volatile("s_waitcnt vmcnt(8)" ::: "memory");
    } else {
      asm volatile("s_waitcnt vmcnt(0)" ::: "memory");
    }
    __builtin_amdgcn_s_barrier();
    __builtin_amdgcn_sched_barrier(0);
#pragma unroll
    for (int kk = 0; kk < 2; ++kk) {
      bf16x8 aF[8], bF[4];
#pragma unroll
      for (int m = 0; m < 8; ++m) {
        int row = wr * 128 + m * 16 + lrow;
        int ch = (kk * 4 + lk) ^ (row & 7);
        aF[m] = *reinterpret_cast<const bf16x8*>(&lds[cur][row * 64 + ch * 8]);
      }
#pragma unroll
      for (int n = 0; n < 4; ++n) {
        int row = wc * 64 + n * 16 + lrow;
        int ch = (kk * 4 + lk) ^ (row & 7);
        bF[n] = *reinterpret_cast<const bf16x8*>(&lds[cur][16384 + row * 64 + ch * 8]);
      }
#pragma unroll
      for (int m = 0; m < 8; ++m)
#pragma unroll
        for (int n = 0; n < 4; ++n)
          acc[m][n] = __builtin_amdgcn_mfma_f32_16x16x32_bf16(
              aF[m], bF[n], acc[m][n], 0, 0, 0);
    }
    __builtin_amdgcn_sched_barrier(0);
    __builtin_amdgcn_s_barrier();
  }

#pragma unroll
  for (int m = 0; m < 8; ++m) {
#pragma unroll
    for (int n = 0; n < 4; ++n) {
      int col = bn + wc * 64 + n * 16 + lrow;
#pragma unroll
      for (int r = 0; r < 4; ++r) {
        int row = bm + wr * 128 + m * 16 + lk * 4 + r;
        float v2 = acc[m][n][r];
        if (MODE == 1) Cb[(size_t)row * DIM_ + col] = f2b(v2);
        else Cf[(size_t)row * DIM_ + col] = v2;
      }
    }
  }
}

// ---------------------------------------------------------------------------
// LayerNorm over last dim (1024) of conv partials p0+p1 (f32).
// K half -> Kb[bh][256][64] row-major; V half -> Vb[bh][256][64] row-major.
// ---------------------------------------------------------------------------
__global__ __launch_bounds__(256) void ln_kernel(
    const float* __restrict__ kvp0, const float* __restrict__ kvp1,
    const float* __restrict__ gamma, const float* __restrict__ beta,
    ushort* __restrict__ Kb, ushort* __restrict__ Vb) {
  const int p = blockIdx.x, tid = threadIdx.x;
  float4 a = reinterpret_cast<const float4*>(kvp0 + (size_t)p * CDIM)[tid];
  float4 b4 = reinterpret_cast<const float4*>(kvp1 + (size_t)p * CDIM)[tid];
  float4 x = make_float4(a.x + b4.x, a.y + b4.y, a.z + b4.z, a.w + b4.w);
  float s = x.x + x.y + x.z + x.w;
  float ss = x.x * x.x + x.y * x.y + x.z * x.z + x.w * x.w;
#pragma unroll
  for (int off = 32; off > 0; off >>= 1) {
    s += __shfl_down(s, off);
    ss += __shfl_down(ss, off);
  }
  __shared__ float sb[4], ssb[4];
  if ((tid & 63) == 0) { sb[tid >> 6] = s; ssb[tid >> 6] = ss; }
  __syncthreads();
  float tot = sb[0] + sb[1] + sb[2] + sb[3];
  float tot2 = ssb[0] + ssb[1] + ssb[2] + ssb[3];
  float mu = tot * (1.f / CDIM);
  float var = tot2 * (1.f / CDIM) - mu * mu;
  float rstd = rsqrtf(var + EPS_);
  float4 g = reinterpret_cast<const float4*>(gamma)[tid];
  float4 bb = reinterpret_cast<const float4*>(beta)[tid];
  ushort4 o;
  o.x = f2b((x.x - mu) * rstd * g.x + bb.x);
  o.y = f2b((x.y - mu) * rstd * g.y + bb.y);
  o.z = f2b((x.z - mu) * rstd * g.z + bb.z);
  o.w = f2b((x.w - mu) * rstd * g.w + bb.w);
  int b = p >> 8, j = p & 255;
  int c = tid * 4;
  if (c < DIM_) {
    int h = c >> 6, d = c & 63;
    *reinterpret_cast<ushort4*>(&Kb[(((size_t)(b * 8 + h)) * M2 + j) * HD_ + d]) = o;
  } else {
    int c2 = c - DIM_;
    int h = c2 >> 6, d = c2 & 63;
    *reinterpret_cast<ushort4*>(&Vb[(((size_t)(b * 8 + h)) * M2 + j) * HD_ + d]) = o;
  }
}

// ---------------------------------------------------------------------------
// V transpose: Vb[bh][256 j][64 d] -> Vt[bh][64 d][256 j] via LDS 64x65
// padded tiles. One block per bh, 256 threads, 4 j-chunks.
// ---------------------------------------------------------------------------
__global__ __launch_bounds__(256) void vtrans_kernel(
    const ushort* __restrict__ Vb, ushort* __restrict__ Vt) {
  __shared__ ushort t[64][65];
  const int bh = blockIdx.x, tid = threadIdx.x;
  const ushort* src = Vb + (size_t)bh * M2 * HD_;
  ushort* dst = Vt + (size_t)bh * HD_ * M2;
  for (int j0 = 0; j0 < M2; j0 += 64) {
    __syncthreads();                     // guard previous tile's reads
#pragma unroll
    for (int it = 0; it < 2; ++it) {
      int s = it * 256 + tid;            // 0..511
      int j = s >> 3, d0 = (s & 7) * 8;
      bf16x8 v = *reinterpret_cast<const bf16x8*>(src + (size_t)(j0 + j) * HD_ + d0);
#pragma unroll
      for (int e = 0; e < 8; ++e) t[d0 + e][j] = (ushort)v[e];
    }
    __syncthreads();
#pragma unroll
    for (int it = 0; it < 2; ++it) {
      int s = it * 256 + tid;
      int d = s >> 3, jj0 = (s & 7) * 8;
      bf16x8 o;
#pragma unroll
      for (int e = 0; e < 8; ++e) o[e] = (short)t[d][jj0 + e];
      *reinterpret_cast<bf16x8*>(dst + (size_t)d * M2 + j0 + jj0) = o;
    }
  }
}

// ---------------------------------------------------------------------------
// MFMA attention (R12): ONE block per (b,h), 512 threads = 8 waves, K/V
// staged once, single barrier, per-wave private P. LDS 128 KiB.
// ---------------------------------------------------------------------------
__global__ __launch_bounds__(512, 2) void attn_mfma_kernel(
    const ushort* __restrict__ qb, const ushort* __restrict__ Kb,
    const ushort* __restrict__ Vt, ushort* __restrict__ attob) {
  __shared__ __align__(16) char lds[131072];
  char* lp = lds;
  const int tid = threadIdx.x;
  const int lane = tid & 63, wid = tid >> 6;   // wid 0..7
  const int lr = lane & 15, lk = lane >> 4;
  const int bh = blockIdx.x;
  const int b = bh >> 3, h = bh & 7;

  auto ks_byte = [](int j, int d) -> int {            // K[256][64] @0
    return (j << 7) + (((d << 1)) ^ ((j & 7) << 4));
  };
  auto vt_byte = [](int d, int j) -> int {            // V^T[64][256] @32K
    return 32768 + (d << 9) + (((j << 1)) ^ ((d & 7) << 4));
  };
  auto p_byte = [](int w, int q4, int kv) -> int {    // P per wave @64K
    return 65536 + (w << 13) + (q4 << 9) + (((kv << 1)) ^ ((q4 & 7) << 4));
  };

  const ushort* Khead  = Kb + (size_t)bh * M2 * HD_;   // [256][64]
  const ushort* Vthead = Vt + (size_t)bh * HD_ * M2;   // [64][256]

#pragma unroll
  for (int it = 0; it < 4; ++it) {
    int o = (it * 512 + tid) * 16;
    int j = o >> 7, c = (o >> 4) & 7;
    int cl = c ^ (j & 7);
    __builtin_amdgcn_global_load_lds((gas_t*)(Khead + j * HD_ + cl * 8),
        (las_t*)(lp + o), 16, 0, 0);
  }
#pragma unroll
  for (int it = 0; it < 4; ++it) {
    int o = (it * 512 + tid) * 16;
    int d = o >> 9, c = (o >> 4) & 31;
    int cl = c ^ (d & 7);
    __builtin_amdgcn_global_load_lds((gas_t*)(Vthead + d * M2 + cl * 8),
        (las_t*)(lp + 32768 + o), 16, 0, 0);
  }

  __syncthreads();   // the ONLY block-wide barrier

  for (int qp = 0; qp < 4; ++qp) {
    const int qbase = qp * 256 + wid * 32;
    bf16x8 qf[2][2];
#pragma unroll
    for (int mf = 0; mf < 2; ++mf)
#pragma unroll
      for (int ks = 0; ks < 2; ++ks)
        qf[mf][ks] = *reinterpret_cast<const bf16x8*>(
            qb + ((size_t)(b * N_ + qbase + mf * 16 + lr)) * DIM_ + h * HD_ + ks * 32 + lk * 8);

    f32x4_t sacc[2][16] = {};
    __builtin_amdgcn_s_setprio(1);
#pragma unroll
    for (int ks = 0; ks < 2; ++ks) {
#pragma unroll
      for (int nj = 0; nj < 16; ++nj) {
        bf16x8 kf = *reinterpret_cast<const bf16x8*>(
            lp + ks_byte(nj * 16 + lr, ks * 32 + lk * 8));
        sacc[0][nj] = __builtin_amdgcn_mfma_f32_16x16x32_bf16(qf[0][ks], kf, sacc[0][nj], 0, 0, 0);
        sacc[1][nj] = __builtin_amdgcn_mfma_f32_16x16x32_bf16(qf[1][ks], kf, sacc[1][nj], 0, 0, 0);
      }
    }
    __builtin_amdgcn_s_setprio(0);

    float linv[2][4];
    f32x4_t oacc[2][4] = {};
#pragma unroll
    for (int mf = 0; mf < 2; ++mf) {
#pragma unroll
      for (int r = 0; r < 4; ++r) {
        float pv[16];
        float sum = 0.f;
#pragma unroll
        for (int nj = 0; nj < 16; ++nj) {
          pv[nj] = __expf(sacc[mf][nj][r] * SCALE_);
          sum += pv[nj];
        }
        sum += __shfl_xor(sum, 1);
        sum += __shfl_xor(sum, 2);
        sum += __shfl_xor(sum, 4);
        sum += __shfl_xor(sum, 8);
        linv[mf][r] = 1.f / sum;
        int q4 = lk * 4 + r;
#pragma unroll
        for (int nj = 0; nj < 16; ++nj)
          *reinterpret_cast<ushort*>(lp + p_byte(wid, q4, nj * 16 + lr)) = f2b(pv[nj]);
      }
      __builtin_amdgcn_s_setprio(1);
#pragma unroll
      for (int ks2 = 0; ks2 < 8; ++ks2) {
        bf16x8 pf = *reinterpret_cast<const bf16x8*>(
            lp + p_byte(wid, lr, ks2 * 32 + lk * 8));
#pragma unroll
        for (int df = 0; df < 4; ++df) {
          bf16x8 vf = *reinterpret_cast<const bf16x8*>(
              lp + vt_byte(df * 16 + lr, ks2 * 32 + lk * 8));
          oacc[mf][df] = __builtin_amdgcn_mfma_f32_16x16x32_bf16(pf, vf, oacc[mf][df], 0, 0, 0);
        }
      }
      __builtin_amdgcn_s_setprio(0);
    }

#pragma unroll
    for (int mf = 0; mf < 2; ++mf)
#pragma unroll
      for (int df = 0; df < 4; ++df)
#pragma unroll
        for (int r = 0; r < 4; ++r) {
          int qrow = qbase + mf * 16 + lk * 4 + r;
          int dcol = df * 16 + lr;
          float val = oacc[mf][df][r] * linv[mf][r];
          attob[((size_t)(b * N_ + qrow)) * DIM_ + h * HD_ + dcol] = f2b(val);
        }
  }
}

// ---------------------------------------------------------------------------
extern "C" void kernel_launch(void* const* d_in, const int* in_sizes, int n_in,
                              void* d_out, int out_size, void* d_ws, size_t ws_size,
                              hipStream_t stream) {
  const float* feats  = (const float*)d_in[0];
  const float* W_q    = (const float*)d_in[1];
  const float* conv_w = (const float*)d_in[2];
  const float* conv_b = (const float*)d_in[3];
  const float* ln_g   = (const float*)d_in[4];
  const float* ln_b   = (const float*)d_in[5];
  const float* W_out  = (const float*)d_in[6];
  float* out = (float*)d_out;

  const size_t FP_ELEMS = (size_t)B_ * PW * PW * DIM_;   // 18.94M
  char* ws = (char*)d_ws;
  ushort* featsp = (ushort*)ws;  ws += FP_ELEMS * 2;                  // 37.9 MB
  ushort* qb     = (ushort*)ws;  ws += (size_t)B_ * N_ * DIM_ * 2;    // 33.5 MB
  ushort* attob  = (ushort*)ws;  ws += (size_t)B_ * N_ * DIM_ * 2;    // 33.5 MB
  float*  kvf    = (float*)ws;   ws += (size_t)B_ * M2 * CDIM * 4;    // 33.5 MB
  ushort* convwb = (ushort*)ws;  ws += (size_t)CDIM * KCONV * 2;      //  9.4 MB
  ushort* wqb    = (ushort*)ws;  ws += (size_t)DIM_ * DIM_ * 2;       //  0.5 MB
  ushort* woutb  = (ushort*)ws;  ws += (size_t)DIM_ * DIM_ * 2;       //  0.5 MB
  ushort* Kb     = (ushort*)ws;  ws += (size_t)B_ * HEAD_ * M2 * HD_ * 2;  // 8.4 MB
  ushort* Vt     = (ushort*)ws;  ws += (size_t)B_ * HEAD_ * M2 * HD_ * 2;  // 8.4 MB
  // conv K-split partial #1 aliased onto attob (dead until attention)
  float* kvp1 = (float*)attob;
  // Vb (row-major V) aliased onto convwb (dead after conv256)
  ushort* Vb = convwb;

  // ONE merged prep dispatch (border + feats cast + convw permute + W casts)
  prep_kernel<<<36384, 256, 0, stream>>>(
      feats, featsp, W_q, wqb, W_out, woutb, conv_w, convwb);

  // q = feats @ W_q^T  -> bf16  (256^2-tile engine)
  gemm256_kernel<1><<<dim3(2, 128), 512, 0, stream>>>(
      nullptr, featsp, wqb, nullptr, qb);

  // kv_pre = conv(feats) + bias: 256^2 tile, K-split z=2 (R13 schedule)
  conv256_kernel<<<dim3(CDIM / 256, (B_ * M2) / 256, 2), 512, 0, stream>>>(
      featsp, convwb, conv_b, kvf, kvp1);

  // LayerNorm (sums partials) -> Kb + Vb (both row-major, coalesced)
  ln_kernel<<<B_ * M2, 256, 0, stream>>>(kvf, kvp1, ln_g, ln_b, Kb, Vb);

  // V transpose: Vb -> Vt (LDS-tiled, coalesced)
  vtrans_kernel<<<B_ * HEAD_, 256, 0, stream>>>(Vb, Vt);

  // MFMA attention (one block per bh, single-barrier) -> attob
  attn_mfma_kernel<<<B_ * HEAD_, 512, 0, stream>>>(qb, Kb, Vt, attob);

  // out = attout @ W_out^T  (256^2-tile engine)
  gemm256_kernel<0><<<dim3(2, 128), 512, 0, stream>>>(
      attob, nullptr, woutb, out, nullptr);
}